// Round 17
// baseline (1278.303 us; speedup 1.0000x reference)
//
#include <hip/hip_runtime.h>
#include <hip/hip_bf16.h>
#include <cmath>

#define BN 4
#define HF 256
#define WF 448
#define HWF (HF*WF)   // 114688
#define GBLK 448      // HWF/256

typedef __attribute__((ext_vector_type(8))) short short8v;
typedef __attribute__((ext_vector_type(4))) float float4v;

__device__ __forceinline__ float clampf(float v, float lo, float hi) {
    return fminf(fmaxf(v, lo), hi);
}
__device__ __forceinline__ float bf2f(ushort u) {
    unsigned v = ((unsigned)u) << 16;
    return __builtin_bit_cast(float, v);
}
__device__ __forceinline__ ushort f2bf(float f) {
    unsigned u = __builtin_bit_cast(unsigned, f);
    unsigned r = u + 0x7FFFu + ((u >> 16) & 1u);   // RNE
    return (ushort)(r >> 16);
}
__device__ __forceinline__ uint packhl(float v) {
    unsigned u = __builtin_bit_cast(unsigned, v);
    ushort hi = (ushort)(u >> 16);                 // trunc
    ushort lo = f2bf(v - bf2f(hi));                // exact remainder, RNE
    return ((uint)hi << 16) | lo;
}
__device__ __forceinline__ float unpackhl(uint u) {
    return bf2f((ushort)(u >> 16)) + bf2f((ushort)(u & 0xffffu));
}

// ---- gate conv ----
__global__ void gate_conv_kernel(const float* __restrict__ x,
                                 const float* __restrict__ wr,
                                 const float* __restrict__ br,
                                 double* __restrict__ partial) {
    __shared__ float wsh[32*54];
    __shared__ float bsh[32];
    int tid = threadIdx.x;
    for (int i = tid; i < 32*54; i += 256) wsh[i] = wr[i];
    if (tid < 32) bsh[tid] = br[tid];
    __syncthreads();
    int p = blockIdx.x*256 + tid;
    int y = p / WF, xx = p % WF;
    float acc[32];
    #pragma unroll
    for (int co = 0; co < 32; ++co) acc[co] = bsh[co];
    for (int ci = 0; ci < 6; ++ci) {
        const float* ip = x + (size_t)ci*HWF;
        float v[9];
        #pragma unroll
        for (int ky = 0; ky < 3; ++ky) {
            int iy = y + ky - 1;
            #pragma unroll
            for (int kx = 0; kx < 3; ++kx) {
                int ix = xx + kx - 1;
                v[ky*3+kx] = ((unsigned)iy < HF && (unsigned)ix < WF) ? ip[iy*WF+ix] : 0.0f;
            }
        }
        #pragma unroll
        for (int co = 0; co < 32; ++co) {
            const float* wp = &wsh[co*54 + ci*9];
            #pragma unroll
            for (int t = 0; t < 9; ++t) acc[co] = fmaf(v[t], wp[t], acc[co]);
        }
    }
    __shared__ float red[4][32];
    int lane = tid & 63, wave = tid >> 6;
    #pragma unroll
    for (int co = 0; co < 32; ++co) {
        float s = fmaxf(acc[co], 0.0f);
        for (int off = 32; off > 0; off >>= 1) s += __shfl_down(s, off);
        if (lane == 0) red[wave][co] = s;
    }
    __syncthreads();
    if (tid < 32) {
        double s = (double)red[0][tid] + (double)red[1][tid]
                 + (double)red[2][tid] + (double)red[3][tid];
        partial[tid*GBLK + blockIdx.x] = s;
    }
}

// ---- gate FC ----
__global__ void gate_fc_kernel(const double* __restrict__ partial,
                               const float* __restrict__ wl,
                               const float* __restrict__ bl,
                               float* __restrict__ g) {
    __shared__ double rm[32];
    __shared__ double v[9];
    int i = threadIdx.x;
    if (i < 32) {
        double s = 0.0;
        for (int k = 0; k < GBLK; ++k) s += partial[i*GBLK + k];
        rm[i] = s / (double)HWF;
    }
    __syncthreads();
    if (i < 9) {
        double t = (double)bl[i];
        for (int c = 0; c < 32; ++c) t += rm[c] * (double)wl[i*32+c];
        v[i] = 1.0 / (1.0 + exp(-t));
    }
    __syncthreads();
    if (i == 0) {
        double s = 0.0;
        for (int k = 0; k < 9; ++k) s += v[k];
        for (int k = 0; k < 9; ++k) {
            double vn = v[k] / (s + 1e-6) * 4.5;
            vn = vn < 0.0 ? 0.0 : (vn > 1.0 ? 1.0 : vn);
            g[k] = (float)rint(vn);
        }
    }
}

// ---- weight prep (merged) ----
__device__ __forceinline__ void wprep_one(const float* __restrict__ w, ushort* __restrict__ o,
                                          int idx, int Cout, int Cin, int CoP, int Kpad) {
    int k   = idx % Kpad;
    int co  = (idx / Kpad) % CoP;
    int tap = (idx / (Kpad*CoP)) % 9;
    int pl  = (idx / (Kpad*CoP*9)) % 2;
    int cv  = idx / (Kpad*CoP*9*2);
    float v = 0.0f;
    if (co < Cout && k < Cin)
        v = w[(((size_t)cv*Cout + co)*Cin + k)*9 + tap];
    unsigned u = __builtin_bit_cast(unsigned, v);
    ushort hi = (ushort)(u >> 16);
    o[idx] = (pl == 0) ? hi : f2bf(v - bf2f(hi));
}
__global__ void wprep_all_kernel(const float* __restrict__ w0a, const float* __restrict__ w0b,
                                 const float* __restrict__ wcb,
                                 ushort* __restrict__ a, ushort* __restrict__ b,
                                 ushort* __restrict__ c) {
    const int NA = 9*2*9*48*32;
    const int NB = 9*2*9*96*64;
    const int NC = 36*2*9*96*96;
    int idx = blockIdx.x*blockDim.x + threadIdx.x;
    if (idx < NA) wprep_one(w0a, a, idx, 40, 17, 48, 32);
    else if (idx < NA+NB) wprep_one(w0b, b, idx-NA, 80, 40, 96, 64);
    else if (idx < NA+NB+NC) wprep_one(wcb, c, idx-NA-NB, 80, 80, 96, 96);
}

// ---- init ----
__global__ void init_kernel(const float* __restrict__ x,
                            float* __restrict__ flow, float* __restrict__ mask,
                            float* __restrict__ w0, float* __restrict__ w1) {
    int idx = blockIdx.x * blockDim.x + threadIdx.x;
    if (idx < BN*4*HWF) flow[idx] = 0.0f;
    if (idx < BN*HWF)   mask[idx] = 0.0f;
    if (idx < BN*3*HWF) {
        int b = idx / (3*HWF), r = idx % (3*HWF);
        w0[idx] = x[(size_t)b*6*HWF + r];
        w1[idx] = x[(size_t)b*6*HWF + 3*HWF + r];
    }
}

// ---- prepare pass H (s>1): horizontal resize -> planar f32 [17][B][HF][sw] ----
// NOTE: inter aliases t0 (ring clobbered; haloz after convA re-zeroes it).
__global__ void prep_h_kernel(const float* __restrict__ x,
                              const float* __restrict__ w0buf, const float* __restrict__ w1buf,
                              const float* __restrict__ mask, const float* __restrict__ flow,
                              const float* __restrict__ g, int gi,
                              float* __restrict__ inter, int s, int sw) {
    if (g[gi] == 0.0f) return;
    int idx = blockIdx.x*blockDim.x + threadIdx.x;
    int total = 17*BN*HF*sw;
    if (idx >= total) return;
    int ox = idx % sw;
    int y  = (idx/sw) % HF;
    int b  = (idx/(sw*HF)) % BN;
    int c  = idx/(sw*HF*BN);
    const float* src; float mult = 1.0f;
    if (c < 6)        src = x + ((size_t)b*6 + c)*HWF;
    else if (c < 9)   src = w0buf + ((size_t)b*3 + (c-6))*HWF;
    else if (c < 12)  src = w1buf + ((size_t)b*3 + (c-9))*HWF;
    else if (c == 12) src = mask + (size_t)b*HWF;
    else { src = flow + ((size_t)b*4 + (c-13))*HWF; mult = 1.0f/(float)s; }
    int nt = 2*s;
    float posx = (ox + 0.5f)*(float)s - 0.5f;
    int jx0 = s*ox - s/2;
    const float* rp = src + (size_t)y*WF;
    float acc = 0.f, sx = 0.f;
    for (int k = 0; k < nt; ++k) {
        int j = jx0 + k;
        float ww = 1.0f - fabsf((float)j - posx)/(float)s;
        if (j < 0 || j >= WF) ww = 0.f;
        sx += ww;
        if (ww != 0.f) acc += ww * rp[j];
    }
    inter[idx] = acc * mult / sx;
}

// ---- prepare pass V (s>1): vertical resize + pack -> [b][sh+1][sw+1][17] ----
__global__ void prep_v_kernel(const float* __restrict__ inter,
                              const float* __restrict__ g, int gi,
                              uint* __restrict__ t, int s, int sh, int sw) {
    if (g[gi] == 0.0f) return;
    int SW1 = sw+1, SH1 = sh+1;
    int idx = blockIdx.x*blockDim.x + threadIdx.x;
    int total = BN*SH1*SW1*4;
    if (idx >= total) return;
    int cg  = idx & 3;
    int pix = idx >> 2;
    int ox = pix % SW1;
    int oy = (pix/SW1) % SH1;
    int b  = pix/(SW1*SH1);
    const int startA[4] = {0,5,9,13};
    const int cntA[4]   = {5,4,4,4};
    int cs = startA[cg], cn = cntA[cg];
    uint* dst = t + (size_t)pix*17 + cs;
    if (ox == sw || oy == sh) {
        for (int c = 0; c < cn; ++c) dst[c] = 0u;
        return;
    }
    int nt = 2*s;
    float posy = (oy + 0.5f)*(float)s - 0.5f;
    int jy0 = s*oy - s/2;
    float wy[8]; float sy = 0.f;
    for (int k = 0; k < nt; ++k) {
        int j = jy0 + k;
        float ww = 1.0f - fabsf((float)j - posy)/(float)s;
        if (j < 0 || j >= HF) ww = 0.f;
        wy[k] = ww; sy += ww;
    }
    float inv = 1.0f / sy;
    for (int c = 0; c < cn; ++c) {
        const float* ip = inter + ((size_t)((cs+c)*BN + b)*HF)*sw + ox;
        float acc = 0.f;
        for (int k = 0; k < nt; ++k) {
            if (wy[k] != 0.f) acc += wy[k] * ip[(size_t)(jy0 + k)*sw];
        }
        dst[c] = packhl(acc * inv);
    }
}

// ---- halo zero (gated, per block, after convA): t0 ring + t1/ra/rb rings ----
__global__ void haloz_kernel(uint* __restrict__ t0, uint* __restrict__ t1,
                             uint* __restrict__ ra, uint* __restrict__ rb,
                             const float* __restrict__ g, int gi,
                             int h, int w, int h2, int w2) {
    if (g[gi] == 0.0f) return;
    int W1 = w+1, H1 = h+1;
    int idx = blockIdx.x*blockDim.x + threadIdx.x;
    if (idx >= BN*H1*W1) return;
    int px = idx % (H1*W1);
    int b  = idx / (H1*W1);
    int x = px % W1, y = px / W1;
    if (y == h || x == w) {
        uint* p = t0 + ((size_t)b*H1*W1 + px)*40;
        for (int c = 0; c < 40; ++c) p[c] = 0u;
    }
    int W2 = w2+2, H2 = h2+2;
    if (y < H2 && x < W2 && (y == 0 || y == H2-1 || x == 0 || x == W2-1)) {
        size_t o = ((size_t)b*H2*W2 + (size_t)y*W2 + x)*80;
        for (int c = 0; c < 80; ++c) { t1[o+c] = 0u; ra[o+c] = 0u; rb[o+c] = 0u; }
    }
}

// ---- software-pipelined packed-NHWC split-bf16 MFMA conv ----
// 1 wave/block; tile = 16 px x R rows; ring-3 prefetch, COMPUTE(s) before ISSUE(s+3).
template<int S, int CIN, int COUT, int SPLIT, int R>
__global__ __launch_bounds__(64)
void conv_pk_kernel(const uint* __restrict__ in, int inWP, size_t inBS,
                    const ushort* __restrict__ wt,
                    const float* __restrict__ bias,
                    const uint* __restrict__ resid,
                    const float* __restrict__ g, int gi,
                    uint* __restrict__ out, int outWP, size_t outBS,
                    int Hout, int Wout) {
    if (g[gi] == 0.0f) return;
    constexpr int KPAD  = ((CIN + 31)/32)*32;
    constexpr int KC    = KPAD/32;
    constexpr int COP   = (SPLIT == 2) ? 96 : 48;
    constexpr int NSTEP = KC*9;
    constexpr int PADO  = (S == 1) ? 1 : 0;
    constexpr size_t LOFF = (size_t)9*COP*KPAD;

    int ntx = (Wout + 15)/16;
    int nty = Hout/R;
    int bx  = blockIdx.x % ntx;
    int t2  = blockIdx.x / ntx;
    int by  = t2 % nty; t2 /= nty;
    int half = t2 % SPLIT;
    int b    = t2 / SPLIT;
    int coB  = half*40;

    int lane = threadIdx.x;
    int l15 = lane & 15, l4 = lane >> 4;
    int ox  = bx*16 + l15;
    int oy0 = by*R;

    float4v acc[R][3];
    #pragma unroll
    for (int n = 0; n < R; ++n)
        #pragma unroll
        for (int m = 0; m < 3; ++m)
            acc[n][m] = (float4v){0.f,0.f,0.f,0.f};

    const uint* inb = in + (size_t)b*inBS;
    const uint* bbase[R];
    #pragma unroll
    for (int n = 0; n < R; ++n) {
        int iy = (oy0 + n)*S - PADO;
        int ix = ox*S - PADO;
        bbase[n] = inb + ((size_t)iy*inWP + ix)*CIN + l4*8;
    }
    const ushort* wbase = wt + ((size_t)(coB + l15))*KPAD + l4*8;

    short8v whA[3][3], wlA[3][3];
    uint bu[3][R][8];

    auto ISSUE = [&](int s) {
        int tap = s % 9, kc = s / 9;
        int dy = tap/3, dx = tap%3;
        int slot = s % 3;
        #pragma unroll
        for (int n = 0; n < R; ++n) {
            const uint* p = bbase[n] + ((size_t)dy*inWP + dx)*CIN + kc*32;
            __builtin_memcpy(&bu[slot][n][0], p, 32);
        }
        #pragma unroll
        for (int m = 0; m < 3; ++m) {
            const ushort* wp = wbase + (size_t)(tap*COP + m*16)*KPAD + kc*32;
            whA[slot][m] = *(const short8v*)wp;
            wlA[slot][m] = *(const short8v*)(wp + LOFF);
        }
    };
    auto COMPUTE = [&](int s) {
        int slot = s % 3;
        short8v bhi[R], blo[R];
        #pragma unroll
        for (int n = 0; n < R; ++n)
            #pragma unroll
            for (int j = 0; j < 8; ++j) {
                bhi[n][j] = (short)(bu[slot][n][j] >> 16);
                blo[n][j] = (short)(bu[slot][n][j] & 0xffffu);
            }
        #pragma unroll
        for (int m = 0; m < 3; ++m)
            #pragma unroll
            for (int n = 0; n < R; ++n) {
                acc[n][m] = __builtin_amdgcn_mfma_f32_16x16x32_bf16(whA[slot][m], bhi[n], acc[n][m], 0, 0, 0);
                acc[n][m] = __builtin_amdgcn_mfma_f32_16x16x32_bf16(whA[slot][m], blo[n], acc[n][m], 0, 0, 0);
                acc[n][m] = __builtin_amdgcn_mfma_f32_16x16x32_bf16(wlA[slot][m], bhi[n], acc[n][m], 0, 0, 0);
            }
    };

    ISSUE(0);
    if (NSTEP > 1) ISSUE(1);
    if (NSTEP > 2) ISSUE(2);
    #pragma unroll
    for (int s = 0; s < NSTEP; ++s) {
        COMPUTE(s);
        if (s + 3 < NSTEP) ISSUE(s + 3);
    }

    if (ox < Wout) {
        #pragma unroll
        for (int n = 0; n < R; ++n) {
            int oy = oy0 + n;
            size_t pbase = (size_t)b*outBS + ((size_t)oy*outWP + ox)*COUT + coB;
            #pragma unroll
            for (int m = 0; m < 3; ++m)
                #pragma unroll
                for (int r = 0; r < 4; ++r) {
                    int rel = m*16 + l4*4 + r;
                    if (rel < 40) {
                        float v = fmaxf(acc[n][m][r] + bias[coB + rel], 0.0f);
                        if (resid) v += unpackhl(resid[pbase + rel]);
                        out[pbase + rel] = packhl(v);
                    }
                }
        }
    }
}

// ---- transposed conv 4x4 s2, packed-NHWC input ----
__global__ void deconv_kernel(const uint* __restrict__ t, int WP, size_t BS,
                              const float* __restrict__ wl,
                              const float* __restrict__ bl,
                              const float* __restrict__ g, int gi,
                              float* __restrict__ out,
                              int h2, int w2) {
    if (g[gi] == 0.0f) return;
    int ho = 2*h2, wo = 2*w2;
    int idx = blockIdx.x * blockDim.x + threadIdx.x;
    int total = BN*5*ho*wo;
    if (idx >= total) return;
    int xx = idx % wo;
    int y  = (idx / wo) % ho;
    int o  = (idx / (wo*ho)) % 5;
    int b  = idx / (wo*ho*5);
    float acc = bl[o];
    int p = y & 1, q = xx & 1;
    const uint* tb = t + (size_t)b*BS;
    for (int dy = 0; dy < 2; ++dy) {
        int ky = p + 2*dy;
        int iy = (y + ky - 2) >> 1;
        if ((unsigned)iy >= (unsigned)h2) continue;
        for (int dx = 0; dx < 2; ++dx) {
            int kx = q + 2*dx;
            int ix = (xx + kx - 2) >> 1;
            if ((unsigned)ix >= (unsigned)w2) continue;
            const uint* tp = tb + ((size_t)iy*WP + ix)*80;
            const float* wp = wl + (size_t)o*80*16 + ky*4 + kx;
            for (int i = 0; i < 80; ++i)
                acc += unpackhl(tp[i]) * wp[i*16];
        }
    }
    out[idx] = acc;
}

// ---- fused upsample+accum+warp; MODE 0: gated, write flow/mask/w0/w1
//      MODE 1: ungated, write flow/mask + packed tin + tin halo
//      MODE 2: ungated, write final output only ----
template<int MODE>
__global__ void upwarp_kernel(const float* __restrict__ tmp,
                              const float* __restrict__ x,
                              const float* __restrict__ g, int gi,
                              float* __restrict__ flow, float* __restrict__ mask,
                              float* __restrict__ w0, float* __restrict__ w1,
                              uint* __restrict__ tin, float* __restrict__ outp,
                              int h, int w, int f, float fdscale) {
    float gg = g[gi];
    if (MODE == 0 && gg == 0.0f) return;
    int idx = blockIdx.x * blockDim.x + threadIdx.x;
    if (idx >= BN*HWF) return;
    if (MODE == 1 && idx < BN*705) {   // zero tin halo (row 256 + col 448)
        int b = idx / 705, k = idx % 705;
        int hy, hx;
        if (k < 449) { hy = 256; hx = k; } else { hy = k - 449; hx = 448; }
        uint* hd = tin + (((size_t)b*257 + hy)*449 + hx)*17;
        #pragma unroll
        for (int c = 0; c < 17; ++c) hd[c] = 0u;
    }
    int p2 = idx % HWF;
    int b  = idx / HWF;
    int xx = p2 % WF, y = p2 / WF;

    float posy = (y + 0.5f)/(float)f - 0.5f;
    float posx = (xx + 0.5f)/(float)f - 0.5f;
    float y0f = floorf(posy), x0f = floorf(posx);
    int jy0 = (int)y0f, jx0 = (int)x0f;
    float fy = posy - y0f, fx = posx - x0f;
    int jy1 = min(jy0 + 1, h-1), jx1 = min(jx0 + 1, w-1);
    jy0 = max(jy0, 0); jx0 = max(jx0, 0);
    float w00 = (1-fx)*(1-fy), w01 = fx*(1-fy), w10 = (1-fx)*fy, w11 = fx*fy;

    float fl[4];
    #pragma unroll
    for (int c = 0; c < 4; ++c) {
        const float* tp = tmp + ((size_t)(b*5 + c))*h*w;
        float val = tp[jy0*w+jx0]*w00 + tp[jy0*w+jx1]*w01 + tp[jy1*w+jx0]*w10 + tp[jy1*w+jx1]*w11;
        size_t fo = ((size_t)b*4 + c)*HWF + p2;
        float nf = flow[fo] + val * fdscale * gg;
        if (MODE != 2) flow[fo] = nf;
        fl[c] = nf;
    }
    float nm;
    {
        const float* tp = tmp + ((size_t)(b*5 + 4))*h*w;
        float val = tp[jy0*w+jx0]*w00 + tp[jy0*w+jx1]*w01 + tp[jy1*w+jx0]*w10 + tp[jy1*w+jx1]*w11;
        nm = mask[(size_t)b*HWF + p2] + val * gg;
        if (MODE != 2) mask[(size_t)b*HWF + p2] = nm;
    }

    float wv[2][3];
    #pragma unroll
    for (int which = 0; which < 2; ++which) {
        float sx = clampf((float)xx + fl[which*2+0], 0.f, (float)(WF-1));
        float sy = clampf((float)y  + fl[which*2+1], 0.f, (float)(HF-1));
        float sx0f = floorf(sx), sy0f = floorf(sy);
        int ix0 = (int)sx0f, iy0 = (int)sy0f;
        int ix1 = min(ix0 + 1, WF - 1), iy1 = min(iy0 + 1, HF - 1);
        float wx = sx - sx0f, wy = sy - sy0f;
        float a00 = (1-wx)*(1-wy), a01 = wx*(1-wy), a10 = (1-wx)*wy, a11 = wx*wy;
        #pragma unroll
        for (int c = 0; c < 3; ++c) {
            const float* im = x + ((size_t)b*6 + which*3 + c)*HWF;
            wv[which][c] = im[iy0*WF+ix0]*a00 + im[iy0*WF+ix1]*a01
                         + im[iy1*WF+ix0]*a10 + im[iy1*WF+ix1]*a11;
        }
    }

    if (MODE == 0) {
        #pragma unroll
        for (int c = 0; c < 3; ++c) {
            w0[((size_t)b*3 + c)*HWF + p2] = wv[0][c];
            w1[((size_t)b*3 + c)*HWF + p2] = wv[1][c];
        }
    } else if (MODE == 1) {
        uint* dst = tin + (((size_t)b*257 + y)*449 + xx)*17;
        const float* xb = x + (size_t)b*6*HWF;
        #pragma unroll
        for (int c = 0; c < 6; ++c) dst[c] = packhl(xb[(size_t)c*HWF + p2]);
        #pragma unroll
        for (int c = 0; c < 3; ++c) dst[6+c] = packhl(wv[0][c]);
        #pragma unroll
        for (int c = 0; c < 3; ++c) dst[9+c] = packhl(wv[1][c]);
        dst[12] = packhl(nm);
        #pragma unroll
        for (int c = 0; c < 4; ++c) dst[13+c] = packhl(fl[c]);
    } else {
        float m = 1.0f / (1.0f + expf(-nm));
        #pragma unroll
        for (int c = 0; c < 3; ++c) {
            float val = wv[0][c]*m + wv[1][c]*(1.0f - m);
            outp[((size_t)b*3 + c)*HWF + p2] = clampf(val, 0.0f, 1.0f);
        }
    }
}

extern "C" void kernel_launch(void* const* d_in, const int* in_sizes, int n_in,
                              void* d_out, int out_size, void* d_ws, size_t ws_size,
                              hipStream_t stream) {
    const float* x     = (const float*)d_in[0];
    const float* wr    = (const float*)d_in[1];
    const float* br    = (const float*)d_in[2];
    const float* wl    = (const float*)d_in[3];
    const float* bl    = (const float*)d_in[4];
    const float* w0a   = (const float*)d_in[5];
    const float* b0a   = (const float*)d_in[6];
    const float* w0b   = (const float*)d_in[7];
    const float* b0b   = (const float*)d_in[8];
    const float* wcb   = (const float*)d_in[9];
    const float* bcb   = (const float*)d_in[10];
    const float* wlast = (const float*)d_in[11];
    const float* blast = (const float*)d_in[12];

    float* ws       = (float*)d_ws;
    double* partial = (double*)d_ws;
    float* g        = ws + 28672;
    size_t off = 28688;
    float* flow = ws + off; off += (size_t)BN*4*HWF;
    float* mask = ws + off; off += (size_t)BN*1*HWF;
    float* wb0  = ws + off; off += (size_t)BN*3*HWF;
    float* wb1  = ws + off; off += (size_t)BN*3*HWF;
    uint*  tinr = (uint*)(ws + off); off += 7900000;   // tin: BN*257*449*17 = 7,846,724 uints
    uint*  t0   = (uint*)(ws + off); off += 4644000;   // also aliases prep intermediate
    float* tmpb = ws + off; off += (size_t)BN*5*(HF/2)*(WF/2);
    ushort* wTa2 = (ushort*)(ws + off); off += (size_t)9*2*9*48*32/2;
    ushort* wTb2 = (ushort*)(ws + off); off += (size_t)9*2*9*96*64/2;
    ushort* wTc2 = (ushort*)(ws + off); off += (size_t)36*2*9*96*96/2;
    // t1/ra/rb alias into tinr (tin dead after convA; each max 4*66*114*80 = 2,407,680)
    uint* t1 = tinr;
    uint* ra = tinr + 2407680;
    uint* rb = tinr + 4815360;
    float* inter = (float*)t0;     // prep intermediate (t0 interior dead until convA)

    gate_conv_kernel<<<GBLK, 256, 0, stream>>>(x, wr, br, partial);
    gate_fc_kernel<<<1, 64, 0, stream>>>(partial, wl, bl, g);
    {
        int n = 9*2*9*48*32 + 9*2*9*96*64 + 36*2*9*96*96;
        wprep_all_kernel<<<(n+255)/256, 256, 0, stream>>>(w0a, w0b, wcb, wTa2, wTb2, wTc2);
    }
    {
        int n = BN*4*HWF;
        init_kernel<<<(n+255)/256, 256, 0, stream>>>(x, flow, mask, wb0, wb1);
    }
    const int SC[9] = {4,4,4,2,2,2,1,1,1};
    for (int i = 0; i < 9; ++i) {
        int s = SC[i];
        int sh = HF/s, sw = WF/s;
        int h = sh/2, w = sw/2;
        int h2 = h/2, w2 = w/2;
        int tinWP = sw+1;             size_t tinBS = (size_t)(sh+1)*(sw+1)*17;
        int t0WP  = w+1;              size_t t0BS  = (size_t)(h+1)*(w+1)*40;
        int t1WP  = w2+2;             size_t t1BS  = (size_t)(h2+2)*(w2+2)*80;
        size_t ioff = ((size_t)t1WP + 1)*80;
        if (s > 1) {
            int n1 = 17*BN*HF*sw;
            prep_h_kernel<<<(n1+255)/256,256,0,stream>>>(x, wb0, wb1, mask, flow, g, i, inter, s, sw);
            int n2 = BN*(sh+1)*(sw+1)*4;
            prep_v_kernel<<<(n2+255)/256,256,0,stream>>>(inter, g, i, tinr, s, sh, sw);
        }
        // s==1: tin was written by previous block's MODE-1 upwarp
        {   // 17->40 s2, SPLIT=1
            int ntx = (w + 15)/16;
            if (h >= 128) {
                conv_pk_kernel<2,17,40,1,2><<<ntx*(h/2)*BN, 64, 0, stream>>>(
                    tinr, tinWP, tinBS, wTa2 + (size_t)i*2*9*48*32, b0a + i*40, nullptr,
                    g, i, t0, t0WP, t0BS, h, w);
            } else {
                conv_pk_kernel<2,17,40,1,1><<<ntx*h*BN, 64, 0, stream>>>(
                    tinr, tinWP, tinBS, wTa2 + (size_t)i*2*9*48*32, b0a + i*40, nullptr,
                    g, i, t0, t0WP, t0BS, h, w);
            }
        }
        {   // halo zero after convA (tin region now reusable): t0 ring + t1/ra/rb rings
            int n = BN*(h+1)*(w+1);
            haloz_kernel<<<(n+255)/256,256,0,stream>>>(t0, t1, ra, rb, g, i, h, w, h2, w2);
        }
        {   // 40->80 s2, SPLIT=2; R=2 when h2>=32 (halves L2 weight traffic), else R=1
            int ntx = (w2 + 15)/16;
            if (h2 >= 32) {
                conv_pk_kernel<2,40,80,2,2><<<ntx*(h2/2)*2*BN, 64, 0, stream>>>(
                    t0, t0WP, t0BS, wTb2 + (size_t)i*2*9*96*64, b0b + i*80, nullptr,
                    g, i, t1 + ioff, t1WP, t1BS, h2, w2);
            } else {
                conv_pk_kernel<2,40,80,2,1><<<ntx*h2*2*BN, 64, 0, stream>>>(
                    t0, t0WP, t0BS, wTb2 + (size_t)i*2*9*96*64, b0b + i*80, nullptr,
                    g, i, t1 + ioff, t1WP, t1BS, h2, w2);
            }
        }
        {   // 4x 80->80 s1, SPLIT=2; R=2 when h2>=32: t1 -> ra -> rb -> ra -> rb(+resid t1)
            int ntx = (w2 + 15)/16;
            const uint* cin = t1 + ioff;
            uint* couts[4] = {ra, rb, ra, rb};
            for (int j = 0; j < 4; ++j) {
                const uint* res = (j == 3) ? (t1 + ioff) : nullptr;
                if (h2 >= 32) {
                    conv_pk_kernel<1,80,80,2,2><<<ntx*(h2/2)*2*BN, 64, 0, stream>>>(
                        cin, t1WP, t1BS, wTc2 + ((size_t)i*4 + j)*2*9*96*96, bcb + ((size_t)i*4 + j)*80,
                        res, g, i, couts[j] + ioff, t1WP, t1BS, h2, w2);
                } else {
                    conv_pk_kernel<1,80,80,2,1><<<ntx*h2*2*BN, 64, 0, stream>>>(
                        cin, t1WP, t1BS, wTc2 + ((size_t)i*4 + j)*2*9*96*96, bcb + ((size_t)i*4 + j)*80,
                        res, g, i, couts[j] + ioff, t1WP, t1BS, h2, w2);
                }
                cin = couts[j] + ioff;
            }
        }
        {
            int n = BN*5*h*w;
            deconv_kernel<<<(n+255)/256,256,0,stream>>>(rb + ioff, t1WP, t1BS,
                wlast + (size_t)i*5*80*16, blast + i*5, g, i, tmpb, h2, w2);
        }
        {
            int n = BN*HWF;
            int nb = (n+255)/256;
            if (i < 5)
                upwarp_kernel<0><<<nb,256,0,stream>>>(tmpb, x, g, i, flow, mask, wb0, wb1,
                    nullptr, nullptr, h, w, 2*s, (float)(2*s));
            else if (i < 8)
                upwarp_kernel<1><<<nb,256,0,stream>>>(tmpb, x, g, i, flow, mask, wb0, wb1,
                    tinr, nullptr, h, w, 2*s, (float)(2*s));
            else
                upwarp_kernel<2><<<nb,256,0,stream>>>(tmpb, x, g, i, flow, mask, wb0, wb1,
                    nullptr, (float*)d_out, h, w, 2*s, (float)(2*s));
        }
    }
}

// Round 18
// 1238.359 us; speedup vs baseline: 1.0323x; 1.0323x over previous
//
#include <hip/hip_runtime.h>
#include <hip/hip_bf16.h>
#include <cmath>

#define BN 4
#define HF 256
#define WF 448
#define HWF (HF*WF)   // 114688
#define GBLK 448      // HWF/256

typedef __attribute__((ext_vector_type(8))) short short8v;
typedef __attribute__((ext_vector_type(4))) float float4v;

__device__ __forceinline__ float clampf(float v, float lo, float hi) {
    return fminf(fmaxf(v, lo), hi);
}
__device__ __forceinline__ float bf2f(ushort u) {
    unsigned v = ((unsigned)u) << 16;
    return __builtin_bit_cast(float, v);
}
__device__ __forceinline__ ushort f2bf(float f) {
    unsigned u = __builtin_bit_cast(unsigned, f);
    unsigned r = u + 0x7FFFu + ((u >> 16) & 1u);   // RNE
    return (ushort)(r >> 16);
}
__device__ __forceinline__ uint packhl(float v) {
    unsigned u = __builtin_bit_cast(unsigned, v);
    ushort hi = (ushort)(u >> 16);                 // trunc
    ushort lo = f2bf(v - bf2f(hi));                // exact remainder, RNE
    return ((uint)hi << 16) | lo;
}
__device__ __forceinline__ float unpackhl(uint u) {
    return bf2f((ushort)(u >> 16)) + bf2f((ushort)(u & 0xffffu));
}

// ---- gate conv ----
__global__ void gate_conv_kernel(const float* __restrict__ x,
                                 const float* __restrict__ wr,
                                 const float* __restrict__ br,
                                 double* __restrict__ partial) {
    __shared__ float wsh[32*54];
    __shared__ float bsh[32];
    int tid = threadIdx.x;
    for (int i = tid; i < 32*54; i += 256) wsh[i] = wr[i];
    if (tid < 32) bsh[tid] = br[tid];
    __syncthreads();
    int p = blockIdx.x*256 + tid;
    int y = p / WF, xx = p % WF;
    float acc[32];
    #pragma unroll
    for (int co = 0; co < 32; ++co) acc[co] = bsh[co];
    for (int ci = 0; ci < 6; ++ci) {
        const float* ip = x + (size_t)ci*HWF;
        float v[9];
        #pragma unroll
        for (int ky = 0; ky < 3; ++ky) {
            int iy = y + ky - 1;
            #pragma unroll
            for (int kx = 0; kx < 3; ++kx) {
                int ix = xx + kx - 1;
                v[ky*3+kx] = ((unsigned)iy < HF && (unsigned)ix < WF) ? ip[iy*WF+ix] : 0.0f;
            }
        }
        #pragma unroll
        for (int co = 0; co < 32; ++co) {
            const float* wp = &wsh[co*54 + ci*9];
            #pragma unroll
            for (int t = 0; t < 9; ++t) acc[co] = fmaf(v[t], wp[t], acc[co]);
        }
    }
    __shared__ float red[4][32];
    int lane = tid & 63, wave = tid >> 6;
    #pragma unroll
    for (int co = 0; co < 32; ++co) {
        float s = fmaxf(acc[co], 0.0f);
        for (int off = 32; off > 0; off >>= 1) s += __shfl_down(s, off);
        if (lane == 0) red[wave][co] = s;
    }
    __syncthreads();
    if (tid < 32) {
        double s = (double)red[0][tid] + (double)red[1][tid]
                 + (double)red[2][tid] + (double)red[3][tid];
        partial[tid*GBLK + blockIdx.x] = s;
    }
}

// ---- gate FC ----
__global__ void gate_fc_kernel(const double* __restrict__ partial,
                               const float* __restrict__ wl,
                               const float* __restrict__ bl,
                               float* __restrict__ g) {
    __shared__ double rm[32];
    __shared__ double v[9];
    int i = threadIdx.x;
    if (i < 32) {
        double s = 0.0;
        for (int k = 0; k < GBLK; ++k) s += partial[i*GBLK + k];
        rm[i] = s / (double)HWF;
    }
    __syncthreads();
    if (i < 9) {
        double t = (double)bl[i];
        for (int c = 0; c < 32; ++c) t += rm[c] * (double)wl[i*32+c];
        v[i] = 1.0 / (1.0 + exp(-t));
    }
    __syncthreads();
    if (i == 0) {
        double s = 0.0;
        for (int k = 0; k < 9; ++k) s += v[k];
        for (int k = 0; k < 9; ++k) {
            double vn = v[k] / (s + 1e-6) * 4.5;
            vn = vn < 0.0 ? 0.0 : (vn > 1.0 ? 1.0 : vn);
            g[k] = (float)rint(vn);
        }
    }
}

// ---- weight prep (merged) ----
__device__ __forceinline__ void wprep_one(const float* __restrict__ w, ushort* __restrict__ o,
                                          int idx, int Cout, int Cin, int CoP, int Kpad) {
    int k   = idx % Kpad;
    int co  = (idx / Kpad) % CoP;
    int tap = (idx / (Kpad*CoP)) % 9;
    int pl  = (idx / (Kpad*CoP*9)) % 2;
    int cv  = idx / (Kpad*CoP*9*2);
    float v = 0.0f;
    if (co < Cout && k < Cin)
        v = w[(((size_t)cv*Cout + co)*Cin + k)*9 + tap];
    unsigned u = __builtin_bit_cast(unsigned, v);
    ushort hi = (ushort)(u >> 16);
    o[idx] = (pl == 0) ? hi : f2bf(v - bf2f(hi));
}
__global__ void wprep_all_kernel(const float* __restrict__ w0a, const float* __restrict__ w0b,
                                 const float* __restrict__ wcb,
                                 ushort* __restrict__ a, ushort* __restrict__ b,
                                 ushort* __restrict__ c) {
    const int NA = 9*2*9*48*32;
    const int NB = 9*2*9*96*64;
    const int NC = 36*2*9*96*96;
    int idx = blockIdx.x*blockDim.x + threadIdx.x;
    if (idx < NA) wprep_one(w0a, a, idx, 40, 17, 48, 32);
    else if (idx < NA+NB) wprep_one(w0b, b, idx-NA, 80, 40, 96, 64);
    else if (idx < NA+NB+NC) wprep_one(wcb, c, idx-NA-NB, 80, 80, 96, 96);
}

// ---- init ----
__global__ void init_kernel(const float* __restrict__ x,
                            float* __restrict__ flow, float* __restrict__ mask,
                            float* __restrict__ w0, float* __restrict__ w1) {
    int idx = blockIdx.x * blockDim.x + threadIdx.x;
    if (idx < BN*4*HWF) flow[idx] = 0.0f;
    if (idx < BN*HWF)   mask[idx] = 0.0f;
    if (idx < BN*3*HWF) {
        int b = idx / (3*HWF), r = idx % (3*HWF);
        w0[idx] = x[(size_t)b*6*HWF + r];
        w1[idx] = x[(size_t)b*6*HWF + 3*HWF + r];
    }
}

// ---- prepare pass H (s>1): horizontal resize -> planar f32 [17][B][HF][sw] ----
// NOTE: inter aliases t0 (ring clobbered; haloz after convA re-zeroes it).
__global__ void prep_h_kernel(const float* __restrict__ x,
                              const float* __restrict__ w0buf, const float* __restrict__ w1buf,
                              const float* __restrict__ mask, const float* __restrict__ flow,
                              const float* __restrict__ g, int gi,
                              float* __restrict__ inter, int s, int sw) {
    if (g[gi] == 0.0f) return;
    int idx = blockIdx.x*blockDim.x + threadIdx.x;
    int total = 17*BN*HF*sw;
    if (idx >= total) return;
    int ox = idx % sw;
    int y  = (idx/sw) % HF;
    int b  = (idx/(sw*HF)) % BN;
    int c  = idx/(sw*HF*BN);
    const float* src; float mult = 1.0f;
    if (c < 6)        src = x + ((size_t)b*6 + c)*HWF;
    else if (c < 9)   src = w0buf + ((size_t)b*3 + (c-6))*HWF;
    else if (c < 12)  src = w1buf + ((size_t)b*3 + (c-9))*HWF;
    else if (c == 12) src = mask + (size_t)b*HWF;
    else { src = flow + ((size_t)b*4 + (c-13))*HWF; mult = 1.0f/(float)s; }
    int nt = 2*s;
    float posx = (ox + 0.5f)*(float)s - 0.5f;
    int jx0 = s*ox - s/2;
    const float* rp = src + (size_t)y*WF;
    float acc = 0.f, sx = 0.f;
    for (int k = 0; k < nt; ++k) {
        int j = jx0 + k;
        float ww = 1.0f - fabsf((float)j - posx)/(float)s;
        if (j < 0 || j >= WF) ww = 0.f;
        sx += ww;
        if (ww != 0.f) acc += ww * rp[j];
    }
    inter[idx] = acc * mult / sx;
}

// ---- prepare pass V (s>1): vertical resize + pack -> [b][sh+1][sw+1][17] ----
__global__ void prep_v_kernel(const float* __restrict__ inter,
                              const float* __restrict__ g, int gi,
                              uint* __restrict__ t, int s, int sh, int sw) {
    if (g[gi] == 0.0f) return;
    int SW1 = sw+1, SH1 = sh+1;
    int idx = blockIdx.x*blockDim.x + threadIdx.x;
    int total = BN*SH1*SW1*4;
    if (idx >= total) return;
    int cg  = idx & 3;
    int pix = idx >> 2;
    int ox = pix % SW1;
    int oy = (pix/SW1) % SH1;
    int b  = pix/(SW1*SH1);
    const int startA[4] = {0,5,9,13};
    const int cntA[4]   = {5,4,4,4};
    int cs = startA[cg], cn = cntA[cg];
    uint* dst = t + (size_t)pix*17 + cs;
    if (ox == sw || oy == sh) {
        for (int c = 0; c < cn; ++c) dst[c] = 0u;
        return;
    }
    int nt = 2*s;
    float posy = (oy + 0.5f)*(float)s - 0.5f;
    int jy0 = s*oy - s/2;
    float wy[8]; float sy = 0.f;
    for (int k = 0; k < nt; ++k) {
        int j = jy0 + k;
        float ww = 1.0f - fabsf((float)j - posy)/(float)s;
        if (j < 0 || j >= HF) ww = 0.f;
        wy[k] = ww; sy += ww;
    }
    float inv = 1.0f / sy;
    for (int c = 0; c < cn; ++c) {
        const float* ip = inter + ((size_t)((cs+c)*BN + b)*HF)*sw + ox;
        float acc = 0.f;
        for (int k = 0; k < nt; ++k) {
            if (wy[k] != 0.f) acc += wy[k] * ip[(size_t)(jy0 + k)*sw];
        }
        dst[c] = packhl(acc * inv);
    }
}

// ---- halo zero (gated, per block, after convA): t0 ring + t1/ra/rb rings ----
__global__ void haloz_kernel(uint* __restrict__ t0, uint* __restrict__ t1,
                             uint* __restrict__ ra, uint* __restrict__ rb,
                             const float* __restrict__ g, int gi,
                             int h, int w, int h2, int w2) {
    if (g[gi] == 0.0f) return;
    int W1 = w+1, H1 = h+1;
    int idx = blockIdx.x*blockDim.x + threadIdx.x;
    if (idx >= BN*H1*W1) return;
    int px = idx % (H1*W1);
    int b  = idx / (H1*W1);
    int x = px % W1, y = px / W1;
    if (y == h || x == w) {
        uint* p = t0 + ((size_t)b*H1*W1 + px)*40;
        for (int c = 0; c < 40; ++c) p[c] = 0u;
    }
    int W2 = w2+2, H2 = h2+2;
    if (y < H2 && x < W2 && (y == 0 || y == H2-1 || x == 0 || x == W2-1)) {
        size_t o = ((size_t)b*H2*W2 + (size_t)y*W2 + x)*80;
        for (int c = 0; c < 80; ++c) { t1[o+c] = 0u; ra[o+c] = 0u; rb[o+c] = 0u; }
    }
}

// ---- software-pipelined packed-NHWC split-bf16 MFMA conv ----
// 1 wave/block; tile = 16 px x R rows; ring-3 prefetch, COMPUTE(s) before ISSUE(s+3).
template<int S, int CIN, int COUT, int SPLIT, int R>
__global__ __launch_bounds__(64)
void conv_pk_kernel(const uint* __restrict__ in, int inWP, size_t inBS,
                    const ushort* __restrict__ wt,
                    const float* __restrict__ bias,
                    const uint* __restrict__ resid,
                    const float* __restrict__ g, int gi,
                    uint* __restrict__ out, int outWP, size_t outBS,
                    int Hout, int Wout) {
    if (g[gi] == 0.0f) return;
    constexpr int KPAD  = ((CIN + 31)/32)*32;
    constexpr int KC    = KPAD/32;
    constexpr int COP   = (SPLIT == 2) ? 96 : 48;
    constexpr int NSTEP = KC*9;
    constexpr int PADO  = (S == 1) ? 1 : 0;
    constexpr size_t LOFF = (size_t)9*COP*KPAD;

    int ntx = (Wout + 15)/16;
    int nty = Hout/R;
    int bx  = blockIdx.x % ntx;
    int t2  = blockIdx.x / ntx;
    int by  = t2 % nty; t2 /= nty;
    int half = t2 % SPLIT;
    int b    = t2 / SPLIT;
    int coB  = half*40;

    int lane = threadIdx.x;
    int l15 = lane & 15, l4 = lane >> 4;
    int ox  = bx*16 + l15;
    int oy0 = by*R;

    float4v acc[R][3];
    #pragma unroll
    for (int n = 0; n < R; ++n)
        #pragma unroll
        for (int m = 0; m < 3; ++m)
            acc[n][m] = (float4v){0.f,0.f,0.f,0.f};

    const uint* inb = in + (size_t)b*inBS;
    const uint* bbase[R];
    #pragma unroll
    for (int n = 0; n < R; ++n) {
        int iy = (oy0 + n)*S - PADO;
        int ix = ox*S - PADO;
        bbase[n] = inb + ((size_t)iy*inWP + ix)*CIN + l4*8;
    }
    const ushort* wbase = wt + ((size_t)(coB + l15))*KPAD + l4*8;

    short8v whA[3][3], wlA[3][3];
    uint bu[3][R][8];

    auto ISSUE = [&](int s) {
        int tap = s % 9, kc = s / 9;
        int dy = tap/3, dx = tap%3;
        int slot = s % 3;
        #pragma unroll
        for (int n = 0; n < R; ++n) {
            const uint* p = bbase[n] + ((size_t)dy*inWP + dx)*CIN + kc*32;
            __builtin_memcpy(&bu[slot][n][0], p, 32);
        }
        #pragma unroll
        for (int m = 0; m < 3; ++m) {
            const ushort* wp = wbase + (size_t)(tap*COP + m*16)*KPAD + kc*32;
            whA[slot][m] = *(const short8v*)wp;
            wlA[slot][m] = *(const short8v*)(wp + LOFF);
        }
    };
    auto COMPUTE = [&](int s) {
        int slot = s % 3;
        short8v bhi[R], blo[R];
        #pragma unroll
        for (int n = 0; n < R; ++n)
            #pragma unroll
            for (int j = 0; j < 8; ++j) {
                bhi[n][j] = (short)(bu[slot][n][j] >> 16);
                blo[n][j] = (short)(bu[slot][n][j] & 0xffffu);
            }
        #pragma unroll
        for (int m = 0; m < 3; ++m)
            #pragma unroll
            for (int n = 0; n < R; ++n) {
                acc[n][m] = __builtin_amdgcn_mfma_f32_16x16x32_bf16(whA[slot][m], bhi[n], acc[n][m], 0, 0, 0);
                acc[n][m] = __builtin_amdgcn_mfma_f32_16x16x32_bf16(whA[slot][m], blo[n], acc[n][m], 0, 0, 0);
                acc[n][m] = __builtin_amdgcn_mfma_f32_16x16x32_bf16(wlA[slot][m], bhi[n], acc[n][m], 0, 0, 0);
            }
    };

    ISSUE(0);
    if (NSTEP > 1) ISSUE(1);
    if (NSTEP > 2) ISSUE(2);
    #pragma unroll
    for (int s = 0; s < NSTEP; ++s) {
        COMPUTE(s);
        if (s + 3 < NSTEP) ISSUE(s + 3);
    }

    if (ox < Wout) {
        #pragma unroll
        for (int n = 0; n < R; ++n) {
            int oy = oy0 + n;
            size_t pbase = (size_t)b*outBS + ((size_t)oy*outWP + ox)*COUT + coB;
            #pragma unroll
            for (int m = 0; m < 3; ++m)
                #pragma unroll
                for (int r = 0; r < 4; ++r) {
                    int rel = m*16 + l4*4 + r;
                    if (rel < 40) {
                        float v = fmaxf(acc[n][m][r] + bias[coB + rel], 0.0f);
                        if (resid) v += unpackhl(resid[pbase + rel]);
                        out[pbase + rel] = packhl(v);
                    }
                }
        }
    }
}

// ---- transposed conv 4x4 s2, packed-NHWC input ----
__global__ void deconv_kernel(const uint* __restrict__ t, int WP, size_t BS,
                              const float* __restrict__ wl,
                              const float* __restrict__ bl,
                              const float* __restrict__ g, int gi,
                              float* __restrict__ out,
                              int h2, int w2) {
    if (g[gi] == 0.0f) return;
    int ho = 2*h2, wo = 2*w2;
    int idx = blockIdx.x * blockDim.x + threadIdx.x;
    int total = BN*5*ho*wo;
    if (idx >= total) return;
    int xx = idx % wo;
    int y  = (idx / wo) % ho;
    int o  = (idx / (wo*ho)) % 5;
    int b  = idx / (wo*ho*5);
    float acc = bl[o];
    int p = y & 1, q = xx & 1;
    const uint* tb = t + (size_t)b*BS;
    for (int dy = 0; dy < 2; ++dy) {
        int ky = p + 2*dy;
        int iy = (y + ky - 2) >> 1;
        if ((unsigned)iy >= (unsigned)h2) continue;
        for (int dx = 0; dx < 2; ++dx) {
            int kx = q + 2*dx;
            int ix = (xx + kx - 2) >> 1;
            if ((unsigned)ix >= (unsigned)w2) continue;
            const uint* tp = tb + ((size_t)iy*WP + ix)*80;
            const float* wp = wl + (size_t)o*80*16 + ky*4 + kx;
            for (int i = 0; i < 80; ++i)
                acc += unpackhl(tp[i]) * wp[i*16];
        }
    }
    out[idx] = acc;
}

// ---- fused upsample+accum+warp; MODE 0: gated, write flow/mask/w0/w1
//      MODE 1: ungated, write flow/mask + packed tin + tin halo
//      MODE 2: ungated, write final output only ----
template<int MODE>
__global__ void upwarp_kernel(const float* __restrict__ tmp,
                              const float* __restrict__ x,
                              const float* __restrict__ g, int gi,
                              float* __restrict__ flow, float* __restrict__ mask,
                              float* __restrict__ w0, float* __restrict__ w1,
                              uint* __restrict__ tin, float* __restrict__ outp,
                              int h, int w, int f, float fdscale) {
    float gg = g[gi];
    if (MODE == 0 && gg == 0.0f) return;
    int idx = blockIdx.x * blockDim.x + threadIdx.x;
    if (idx >= BN*HWF) return;
    if (MODE == 1 && idx < BN*705) {   // zero tin halo (row 256 + col 448)
        int b = idx / 705, k = idx % 705;
        int hy, hx;
        if (k < 449) { hy = 256; hx = k; } else { hy = k - 449; hx = 448; }
        uint* hd = tin + (((size_t)b*257 + hy)*449 + hx)*17;
        #pragma unroll
        for (int c = 0; c < 17; ++c) hd[c] = 0u;
    }
    int p2 = idx % HWF;
    int b  = idx / HWF;
    int xx = p2 % WF, y = p2 / WF;

    float posy = (y + 0.5f)/(float)f - 0.5f;
    float posx = (xx + 0.5f)/(float)f - 0.5f;
    float y0f = floorf(posy), x0f = floorf(posx);
    int jy0 = (int)y0f, jx0 = (int)x0f;
    float fy = posy - y0f, fx = posx - x0f;
    int jy1 = min(jy0 + 1, h-1), jx1 = min(jx0 + 1, w-1);
    jy0 = max(jy0, 0); jx0 = max(jx0, 0);
    float w00 = (1-fx)*(1-fy), w01 = fx*(1-fy), w10 = (1-fx)*fy, w11 = fx*fy;

    float fl[4];
    #pragma unroll
    for (int c = 0; c < 4; ++c) {
        const float* tp = tmp + ((size_t)(b*5 + c))*h*w;
        float val = tp[jy0*w+jx0]*w00 + tp[jy0*w+jx1]*w01 + tp[jy1*w+jx0]*w10 + tp[jy1*w+jx1]*w11;
        size_t fo = ((size_t)b*4 + c)*HWF + p2;
        float nf = flow[fo] + val * fdscale * gg;
        if (MODE != 2) flow[fo] = nf;
        fl[c] = nf;
    }
    float nm;
    {
        const float* tp = tmp + ((size_t)(b*5 + 4))*h*w;
        float val = tp[jy0*w+jx0]*w00 + tp[jy0*w+jx1]*w01 + tp[jy1*w+jx0]*w10 + tp[jy1*w+jx1]*w11;
        nm = mask[(size_t)b*HWF + p2] + val * gg;
        if (MODE != 2) mask[(size_t)b*HWF + p2] = nm;
    }

    float wv[2][3];
    #pragma unroll
    for (int which = 0; which < 2; ++which) {
        float sx = clampf((float)xx + fl[which*2+0], 0.f, (float)(WF-1));
        float sy = clampf((float)y  + fl[which*2+1], 0.f, (float)(HF-1));
        float sx0f = floorf(sx), sy0f = floorf(sy);
        int ix0 = (int)sx0f, iy0 = (int)sy0f;
        int ix1 = min(ix0 + 1, WF - 1), iy1 = min(iy0 + 1, HF - 1);
        float wx = sx - sx0f, wy = sy - sy0f;
        float a00 = (1-wx)*(1-wy), a01 = wx*(1-wy), a10 = (1-wx)*wy, a11 = wx*wy;
        #pragma unroll
        for (int c = 0; c < 3; ++c) {
            const float* im = x + ((size_t)b*6 + which*3 + c)*HWF;
            wv[which][c] = im[iy0*WF+ix0]*a00 + im[iy0*WF+ix1]*a01
                         + im[iy1*WF+ix0]*a10 + im[iy1*WF+ix1]*a11;
        }
    }

    if (MODE == 0) {
        #pragma unroll
        for (int c = 0; c < 3; ++c) {
            w0[((size_t)b*3 + c)*HWF + p2] = wv[0][c];
            w1[((size_t)b*3 + c)*HWF + p2] = wv[1][c];
        }
    } else if (MODE == 1) {
        uint* dst = tin + (((size_t)b*257 + y)*449 + xx)*17;
        const float* xb = x + (size_t)b*6*HWF;
        #pragma unroll
        for (int c = 0; c < 6; ++c) dst[c] = packhl(xb[(size_t)c*HWF + p2]);
        #pragma unroll
        for (int c = 0; c < 3; ++c) dst[6+c] = packhl(wv[0][c]);
        #pragma unroll
        for (int c = 0; c < 3; ++c) dst[9+c] = packhl(wv[1][c]);
        dst[12] = packhl(nm);
        #pragma unroll
        for (int c = 0; c < 4; ++c) dst[13+c] = packhl(fl[c]);
    } else {
        float m = 1.0f / (1.0f + expf(-nm));
        #pragma unroll
        for (int c = 0; c < 3; ++c) {
            float val = wv[0][c]*m + wv[1][c]*(1.0f - m);
            outp[((size_t)b*3 + c)*HWF + p2] = clampf(val, 0.0f, 1.0f);
        }
    }
}

extern "C" void kernel_launch(void* const* d_in, const int* in_sizes, int n_in,
                              void* d_out, int out_size, void* d_ws, size_t ws_size,
                              hipStream_t stream) {
    const float* x     = (const float*)d_in[0];
    const float* wr    = (const float*)d_in[1];
    const float* br    = (const float*)d_in[2];
    const float* wl    = (const float*)d_in[3];
    const float* bl    = (const float*)d_in[4];
    const float* w0a   = (const float*)d_in[5];
    const float* b0a   = (const float*)d_in[6];
    const float* w0b   = (const float*)d_in[7];
    const float* b0b   = (const float*)d_in[8];
    const float* wcb   = (const float*)d_in[9];
    const float* bcb   = (const float*)d_in[10];
    const float* wlast = (const float*)d_in[11];
    const float* blast = (const float*)d_in[12];

    float* ws       = (float*)d_ws;
    double* partial = (double*)d_ws;
    float* g        = ws + 28672;
    size_t off = 28688;
    float* flow = ws + off; off += (size_t)BN*4*HWF;
    float* mask = ws + off; off += (size_t)BN*1*HWF;
    float* wb0  = ws + off; off += (size_t)BN*3*HWF;
    float* wb1  = ws + off; off += (size_t)BN*3*HWF;
    uint*  tinr = (uint*)(ws + off); off += 7900000;   // tin: BN*257*449*17 = 7,846,724 uints
    uint*  t0   = (uint*)(ws + off); off += 4644000;   // also aliases prep intermediate
    float* tmpb = ws + off; off += (size_t)BN*5*(HF/2)*(WF/2);
    ushort* wTa2 = (ushort*)(ws + off); off += (size_t)9*2*9*48*32/2;
    ushort* wTb2 = (ushort*)(ws + off); off += (size_t)9*2*9*96*64/2;
    ushort* wTc2 = (ushort*)(ws + off); off += (size_t)36*2*9*96*96/2;
    // t1/ra/rb alias into tinr (tin dead after convA; each max 4*66*114*80 = 2,407,680)
    uint* t1 = tinr;
    uint* ra = tinr + 2407680;
    uint* rb = tinr + 4815360;
    float* inter = (float*)t0;     // prep intermediate (t0 interior dead until convA)

    gate_conv_kernel<<<GBLK, 256, 0, stream>>>(x, wr, br, partial);
    gate_fc_kernel<<<1, 64, 0, stream>>>(partial, wl, bl, g);
    {
        int n = 9*2*9*48*32 + 9*2*9*96*64 + 36*2*9*96*96;
        wprep_all_kernel<<<(n+255)/256, 256, 0, stream>>>(w0a, w0b, wcb, wTa2, wTb2, wTc2);
    }
    {
        int n = BN*4*HWF;
        init_kernel<<<(n+255)/256, 256, 0, stream>>>(x, flow, mask, wb0, wb1);
    }
    const int SC[9] = {4,4,4,2,2,2,1,1,1};
    for (int i = 0; i < 9; ++i) {
        int s = SC[i];
        int sh = HF/s, sw = WF/s;
        int h = sh/2, w = sw/2;
        int h2 = h/2, w2 = w/2;
        int tinWP = sw+1;             size_t tinBS = (size_t)(sh+1)*(sw+1)*17;
        int t0WP  = w+1;              size_t t0BS  = (size_t)(h+1)*(w+1)*40;
        int t1WP  = w2+2;             size_t t1BS  = (size_t)(h2+2)*(w2+2)*80;
        size_t ioff = ((size_t)t1WP + 1)*80;
        if (s > 1) {
            int n1 = 17*BN*HF*sw;
            prep_h_kernel<<<(n1+255)/256,256,0,stream>>>(x, wb0, wb1, mask, flow, g, i, inter, s, sw);
            int n2 = BN*(sh+1)*(sw+1)*4;
            prep_v_kernel<<<(n2+255)/256,256,0,stream>>>(inter, g, i, tinr, s, sh, sw);
        }
        // s==1: tin was written by previous block's MODE-1 upwarp
        {   // 17->40 s2, SPLIT=1
            int ntx = (w + 15)/16;
            if (h >= 128) {
                conv_pk_kernel<2,17,40,1,2><<<ntx*(h/2)*BN, 64, 0, stream>>>(
                    tinr, tinWP, tinBS, wTa2 + (size_t)i*2*9*48*32, b0a + i*40, nullptr,
                    g, i, t0, t0WP, t0BS, h, w);
            } else {
                conv_pk_kernel<2,17,40,1,1><<<ntx*h*BN, 64, 0, stream>>>(
                    tinr, tinWP, tinBS, wTa2 + (size_t)i*2*9*48*32, b0a + i*40, nullptr,
                    g, i, t0, t0WP, t0BS, h, w);
            }
        }
        {   // halo zero after convA (tin region now reusable): t0 ring + t1/ra/rb rings
            int n = BN*(h+1)*(w+1);
            haloz_kernel<<<(n+255)/256,256,0,stream>>>(t0, t1, ra, rb, g, i, h, w, h2, w2);
        }
        {   // 40->80 s2, SPLIT=2, R=1
            int ntx = (w2 + 15)/16;
            conv_pk_kernel<2,40,80,2,1><<<ntx*h2*2*BN, 64, 0, stream>>>(
                t0, t0WP, t0BS, wTb2 + (size_t)i*2*9*96*64, b0b + i*80, nullptr,
                g, i, t1 + ioff, t1WP, t1BS, h2, w2);
        }
        {   // 4x 80->80 s1, SPLIT=2, R=1: t1 -> ra -> rb -> ra -> rb(+resid t1)
            int ntx = (w2 + 15)/16;
            int nblk = ntx*h2*2*BN;
            const uint* cin = t1 + ioff;
            uint* couts[4] = {ra, rb, ra, rb};
            for (int j = 0; j < 4; ++j) {
                const uint* res = (j == 3) ? (t1 + ioff) : nullptr;
                conv_pk_kernel<1,80,80,2,1><<<nblk, 64, 0, stream>>>(
                    cin, t1WP, t1BS, wTc2 + ((size_t)i*4 + j)*2*9*96*96, bcb + ((size_t)i*4 + j)*80,
                    res, g, i, couts[j] + ioff, t1WP, t1BS, h2, w2);
                cin = couts[j] + ioff;
            }
        }
        {
            int n = BN*5*h*w;
            deconv_kernel<<<(n+255)/256,256,0,stream>>>(rb + ioff, t1WP, t1BS,
                wlast + (size_t)i*5*80*16, blast + i*5, g, i, tmpb, h2, w2);
        }
        {
            int n = BN*HWF;
            int nb = (n+255)/256;
            if (i < 5)
                upwarp_kernel<0><<<nb,256,0,stream>>>(tmpb, x, g, i, flow, mask, wb0, wb1,
                    nullptr, nullptr, h, w, 2*s, (float)(2*s));
            else if (i < 8)
                upwarp_kernel<1><<<nb,256,0,stream>>>(tmpb, x, g, i, flow, mask, wb0, wb1,
                    tinr, nullptr, h, w, 2*s, (float)(2*s));
            else
                upwarp_kernel<2><<<nb,256,0,stream>>>(tmpb, x, g, i, flow, mask, wb0, wb1,
                    nullptr, (float*)d_out, h, w, 2*s, (float)(2*s));
        }
    }
}